// Round 1
// baseline (1869.338 us; speedup 1.0000x reference)
//
#include <hip/hip_runtime.h>
#include <hip/hip_bf16.h>

#define N_NODES 50000
#define N_EDGES 400000
#define N_GRAPHS 64
#define HEADS 4
#define GAT_DIM 128
#define FDIM 512   // HEADS*GAT_DIM
#define NEG_SLOPE 0.2f

// ---------------- CSR build ----------------
__global__ void deg_kernel(const int* __restrict__ edst, int* __restrict__ deg) {
    int e = blockIdx.x * blockDim.x + threadIdx.x;
    if (e < N_EDGES) atomicAdd(&deg[edst[e]], 1);
}

// single block, 1024 threads: exclusive scan of deg[N_NODES] -> off[N_NODES+1]
__global__ __launch_bounds__(1024) void scan_kernel(const int* __restrict__ deg,
                                                    int* __restrict__ off) {
    __shared__ int part[1024];
    const int n = N_NODES;
    int t = threadIdx.x;
    int chunk = (n + 1023) / 1024;
    int base = t * chunk;
    int s = 0;
    for (int i = 0; i < chunk; i++) {
        int idx = base + i;
        if (idx < n) s += deg[idx];
    }
    part[t] = s;
    __syncthreads();
    for (int d = 1; d < 1024; d <<= 1) {
        int add = (t >= d) ? part[t - d] : 0;
        __syncthreads();
        part[t] += add;
        __syncthreads();
    }
    int run = part[t] - s;  // exclusive prefix of this thread's chunk
    for (int i = 0; i < chunk; i++) {
        int idx = base + i;
        if (idx < n) { off[idx] = run; run += deg[idx]; }
    }
    if (t == 0) off[n] = part[1023];
}

__global__ void fill_kernel(const int* __restrict__ esrc, const int* __restrict__ edst,
                            const int* __restrict__ off, int* __restrict__ cursor,
                            int* __restrict__ csr_src, int* __restrict__ csr_eid) {
    int e = blockIdx.x * blockDim.x + threadIdx.x;
    if (e >= N_EDGES) return;
    int d = edst[e];
    int pos = off[d] + atomicAdd(&cursor[d], 1);
    csr_src[pos] = esrc[e];
    csr_eid[pos] = e;
}

// ---------------- layer 0 node transform: x[N,3] @ W[3,512] + b ----------------
__global__ void xform0_kernel(const float* __restrict__ x,
                              const float* __restrict__ Wl, const float* __restrict__ bl,
                              const float* __restrict__ Wr, const float* __restrict__ br,
                              float* __restrict__ xl, float* __restrict__ xr) {
    int idx = blockIdx.x * blockDim.x + threadIdx.x;
    if (idx >= N_NODES * FDIM) return;
    int n = idx >> 9;
    int j = idx & 511;
    float x0 = x[n * 3 + 0], x1 = x[n * 3 + 1], x2 = x[n * 3 + 2];
    xl[idx] = fmaf(x0, Wl[j], fmaf(x1, Wl[512 + j], fmaf(x2, Wl[1024 + j], bl[j])));
    xr[idx] = fmaf(x0, Wr[j], fmaf(x1, Wr[512 + j], fmaf(x2, Wr[1024 + j], br[j])));
}

// ---------------- fp32 tiled GEMM: C[M,512] = A[M,128] @ W[128,512] + bias ----------------
#define BM 64
#define BN 64
#define BK 32
__global__ __launch_bounds__(256) void gemm_bias_kernel(const float* __restrict__ A,
                                                        const float* __restrict__ W,
                                                        const float* __restrict__ bias,
                                                        float* __restrict__ C, int M) {
    __shared__ float As[BK][BM + 4];  // +4: keeps float4 alignment, shifts banks
    __shared__ float Bs[BK][BN];
    int bn = blockIdx.x * BN;
    int bm = blockIdx.y * BM;
    int tid = threadIdx.x;
    int tm = tid & 15, tn = tid >> 4;
    float acc[4][4] = {};
    for (int k0 = 0; k0 < 128; k0 += BK) {
#pragma unroll
        for (int i = 0; i < 2; i++) {  // A tile: 64 rows x 32 cols
            int id = tid * 2 + i;      // 0..511
            int row = id >> 3;
            int c4 = (id & 7) * 4;
            float4 v = make_float4(0.f, 0.f, 0.f, 0.f);
            int gr = bm + row;
            if (gr < M) v = *(const float4*)(A + (size_t)gr * 128 + k0 + c4);
            As[c4 + 0][row] = v.x; As[c4 + 1][row] = v.y;
            As[c4 + 2][row] = v.z; As[c4 + 3][row] = v.w;
        }
#pragma unroll
        for (int i = 0; i < 2; i++) {  // B tile: 32 rows x 64 cols
            int id = tid * 2 + i;
            int row = id >> 4;
            int c4 = (id & 15) * 4;
            *(float4*)&Bs[row][c4] = *(const float4*)(W + (size_t)(k0 + row) * 512 + bn + c4);
        }
        __syncthreads();
#pragma unroll
        for (int k = 0; k < BK; k++) {
            float4 a = *(const float4*)&As[k][tm * 4];
            float4 b = *(const float4*)&Bs[k][tn * 4];
            float av[4] = {a.x, a.y, a.z, a.w};
            float bv[4] = {b.x, b.y, b.z, b.w};
#pragma unroll
            for (int i = 0; i < 4; i++)
#pragma unroll
                for (int j = 0; j < 4; j++) acc[i][j] = fmaf(av[i], bv[j], acc[i][j]);
        }
        __syncthreads();
    }
#pragma unroll
    for (int i = 0; i < 4; i++) {
        int gr = bm + tm * 4 + i;
        if (gr >= M) continue;
        int gc = bn + tn * 4;
        float4 o;
        o.x = acc[i][0] + bias[gc + 0];
        o.y = acc[i][1] + bias[gc + 1];
        o.z = acc[i][2] + bias[gc + 2];
        o.w = acc[i][3] + bias[gc + 3];
        *(float4*)(C + (size_t)gr * 512 + gc) = o;
    }
}

// ---------------- edge attention scores: one wave per edge ----------------
__global__ void edge_score_kernel(const int* __restrict__ esrc, const int* __restrict__ edst,
                                  const float* __restrict__ xl, const float* __restrict__ xr,
                                  const float* __restrict__ att, float* __restrict__ escore) {
    int wave = (blockIdx.x * blockDim.x + threadIdx.x) >> 6;
    int lane = threadIdx.x & 63;
    if (wave >= N_EDGES) return;
    int s = esrc[wave], d = edst[wave];
    const float4* pl = (const float4*)(xl + (size_t)s * FDIM + lane * 8);
    const float4* pr = (const float4*)(xr + (size_t)d * FDIM + lane * 8);
    const float4* pa = (const float4*)(att + lane * 8);
    float partial = 0.f;
#pragma unroll
    for (int i = 0; i < 2; i++) {
        float4 a = pl[i], b = pr[i], w = pa[i];
        float m0 = a.x + b.x, m1 = a.y + b.y, m2 = a.z + b.z, m3 = a.w + b.w;
        m0 = m0 > 0.f ? m0 : NEG_SLOPE * m0;
        m1 = m1 > 0.f ? m1 : NEG_SLOPE * m1;
        m2 = m2 > 0.f ? m2 : NEG_SLOPE * m2;
        m3 = m3 > 0.f ? m3 : NEG_SLOPE * m3;
        partial = fmaf(m0, w.x, fmaf(m1, w.y, fmaf(m2, w.z, fmaf(m3, w.w, partial))));
    }
    // reduce within each 16-lane group (one head per group)
    partial += __shfl_xor(partial, 1);
    partial += __shfl_xor(partial, 2);
    partial += __shfl_xor(partial, 4);
    partial += __shfl_xor(partial, 8);
    if ((lane & 15) == 0) escore[(size_t)wave * 4 + (lane >> 4)] = partial;
}

// ---------------- segment softmax: one thread per (node, head) ----------------
__global__ void softmax_kernel(const int* __restrict__ off, const int* __restrict__ csr_eid,
                               const float* __restrict__ escore, float* __restrict__ alpha) {
    int idx = blockIdx.x * blockDim.x + threadIdx.x;
    if (idx >= N_NODES * HEADS) return;
    int n = idx >> 2, h = idx & 3;
    int s = off[n], e = off[n + 1];
    float m = -1e30f;
    for (int p = s; p < e; p++) m = fmaxf(m, escore[(size_t)csr_eid[p] * 4 + h]);
    float sum = 0.f;
    for (int p = s; p < e; p++) {
        float v = expf(escore[(size_t)csr_eid[p] * 4 + h] - m);
        alpha[(size_t)p * 4 + h] = v;
        sum += v;
    }
    if (e > s) {
        float inv = 1.f / sum;
        for (int p = s; p < e; p++) alpha[(size_t)p * 4 + h] *= inv;
    }
}

// ---------------- aggregation + head-mean + bias + ELU: one block (128 thr) per node ----------
__global__ __launch_bounds__(128) void aggregate_kernel(const int* __restrict__ off,
                                                        const int* __restrict__ csr_src,
                                                        const float* __restrict__ alpha,
                                                        const float* __restrict__ xl,
                                                        const float* __restrict__ bias,
                                                        float* __restrict__ hout) {
    int n = blockIdx.x;
    int c = threadIdx.x;  // 0..127
    int s = off[n], e = off[n + 1];
    float acc0 = 0.f, acc1 = 0.f, acc2 = 0.f, acc3 = 0.f;
    for (int p = s; p < e; p++) {
        float4 a = *(const float4*)(alpha + (size_t)p * 4);  // broadcast
        int src = csr_src[p];
        const float* base = xl + (size_t)src * FDIM + c;
        acc0 = fmaf(a.x, base[0], acc0);
        acc1 = fmaf(a.y, base[128], acc1);
        acc2 = fmaf(a.z, base[256], acc2);
        acc3 = fmaf(a.w, base[384], acc3);
    }
    float v = 0.25f * (acc0 + acc1 + acc2 + acc3) + bias[c];
    v = v > 0.f ? v : (expf(v) - 1.f);  // ELU
    hout[(size_t)n * GAT_DIM + c] = v;
}

// ---------------- mean pool over sorted batch (double accumulation) ----------------
#define POOL_CHUNK 512
__global__ __launch_bounds__(128) void pool_kernel(const float* __restrict__ h,
                                                   const int* __restrict__ batch,
                                                   double* __restrict__ psum,
                                                   int* __restrict__ pcnt) {
    int c = threadIdx.x;  // 0..127
    int n0 = blockIdx.x * POOL_CHUNK;
    int n1 = min(n0 + POOL_CHUNK, N_NODES);
    if (n0 >= N_NODES) return;
    double acc = 0.0;
    int cur = batch[n0];
    int cnt = 0;
    for (int n = n0; n < n1; n++) {
        int g = batch[n];
        if (g != cur) {
            atomicAdd(&psum[(size_t)cur * GAT_DIM + c], acc);
            if (c == 0) atomicAdd(&pcnt[cur], cnt);
            acc = 0.0; cnt = 0; cur = g;
        }
        acc += (double)h[(size_t)n * GAT_DIM + c];
        cnt++;
    }
    atomicAdd(&psum[(size_t)cur * GAT_DIM + c], acc);
    if (c == 0) atomicAdd(&pcnt[cur], cnt);
}

// ---------------- final linear: out[64,128] = g @ linW + linb ----------------
__global__ __launch_bounds__(128) void final_kernel(const double* __restrict__ psum,
                                                    const int* __restrict__ pcnt,
                                                    const float* __restrict__ linW,
                                                    const float* __restrict__ linb,
                                                    float* __restrict__ out) {
    int g = blockIdx.x;       // 0..63
    int j = threadIdx.x;      // 0..127
    __shared__ float gv[128];
    float cnt = (float)max(pcnt[g], 1);
    gv[j] = (float)(psum[(size_t)g * 128 + j] / (double)cnt);
    __syncthreads();
    float acc = 0.f;
    for (int c = 0; c < 128; c++) acc = fmaf(gv[c], linW[c * 128 + j], acc);
    out[(size_t)g * 128 + j] = acc + linb[j];
}

extern "C" void kernel_launch(void* const* d_in, const int* in_sizes, int n_in,
                              void* d_out, int out_size, void* d_ws, size_t ws_size,
                              hipStream_t stream) {
    const float* x    = (const float*)d_in[0];
    const int* eidx   = (const int*)d_in[1];
    const int* batch  = (const int*)d_in[2];
    const float* Wl[3] = {(const float*)d_in[3],  (const float*)d_in[9],  (const float*)d_in[15]};
    const float* bl[3] = {(const float*)d_in[4],  (const float*)d_in[10], (const float*)d_in[16]};
    const float* Wr[3] = {(const float*)d_in[5],  (const float*)d_in[11], (const float*)d_in[17]};
    const float* br[3] = {(const float*)d_in[6],  (const float*)d_in[12], (const float*)d_in[18]};
    const float* att[3] = {(const float*)d_in[7], (const float*)d_in[13], (const float*)d_in[19]};
    const float* bb[3] = {(const float*)d_in[8],  (const float*)d_in[14], (const float*)d_in[20]};
    const float* linW = (const float*)d_in[21];
    const float* linb = (const float*)d_in[22];
    float* out = (float*)d_out;

    const int* esrc = eidx;
    const int* edst = eidx + N_EDGES;

    // workspace carve-up (256B aligned)
    char* p = (char*)d_ws;
    auto alloc = [&](size_t bytes) { void* r = (void*)p; p += (bytes + 255) & ~(size_t)255; return r; };
    float* xl      = (float*)alloc((size_t)N_NODES * FDIM * 4);   // 102.4 MB
    float* xr      = (float*)alloc((size_t)N_NODES * FDIM * 4);   // 102.4 MB
    float* escore  = (float*)alloc((size_t)N_EDGES * 4 * 4);      // 6.4 MB
    float* alpha   = (float*)alloc((size_t)N_EDGES * 4 * 4);      // 6.4 MB
    float* hbuf    = (float*)alloc((size_t)N_NODES * GAT_DIM * 4);// 25.6 MB
    int*   deg     = (int*)alloc((size_t)N_NODES * 4);
    int*   off     = (int*)alloc((size_t)(N_NODES + 1) * 4);
    int*   cursor  = (int*)alloc((size_t)N_NODES * 4);
    int*   csr_src = (int*)alloc((size_t)N_EDGES * 4);
    int*   csr_eid = (int*)alloc((size_t)N_EDGES * 4);
    double* psum   = (double*)alloc((size_t)N_GRAPHS * GAT_DIM * 8);
    int*   pcnt    = (int*)alloc((size_t)N_GRAPHS * 4);

    // zero what needs zeroing (ws is poisoned 0xAA before every call)
    hipMemsetAsync(deg, 0, (size_t)N_NODES * 4, stream);
    hipMemsetAsync(cursor, 0, (size_t)N_NODES * 4, stream);
    hipMemsetAsync(psum, 0, (size_t)N_GRAPHS * GAT_DIM * 8, stream);
    hipMemsetAsync(pcnt, 0, (size_t)N_GRAPHS * 4, stream);

    // CSR build (dst is layer-invariant)
    deg_kernel<<<(N_EDGES + 255) / 256, 256, 0, stream>>>(edst, deg);
    scan_kernel<<<1, 1024, 0, stream>>>(deg, off);
    fill_kernel<<<(N_EDGES + 255) / 256, 256, 0, stream>>>(esrc, edst, off, cursor, csr_src, csr_eid);

    const int egrid = (N_EDGES + 3) / 4;          // 4 waves (edges) per 256-thr block
    const int sgrid = (N_NODES * HEADS + 255) / 256;
    dim3 ggrid(512 / BN, (N_NODES + BM - 1) / BM);

    for (int l = 0; l < 3; l++) {
        if (l == 0) {
            xform0_kernel<<<(N_NODES * FDIM + 255) / 256, 256, 0, stream>>>(
                x, Wl[0], bl[0], Wr[0], br[0], xl, xr);
        } else {
            gemm_bias_kernel<<<ggrid, 256, 0, stream>>>(hbuf, Wl[l], bl[l], xl, N_NODES);
            gemm_bias_kernel<<<ggrid, 256, 0, stream>>>(hbuf, Wr[l], br[l], xr, N_NODES);
        }
        edge_score_kernel<<<egrid, 256, 0, stream>>>(esrc, edst, xl, xr, att[l], escore);
        softmax_kernel<<<sgrid, 256, 0, stream>>>(off, csr_eid, escore, alpha);
        aggregate_kernel<<<N_NODES, 128, 0, stream>>>(off, csr_src, alpha, xl, bb[l], hbuf);
    }

    pool_kernel<<<(N_NODES + POOL_CHUNK - 1) / POOL_CHUNK, 128, 0, stream>>>(hbuf, batch, psum, pcnt);
    final_kernel<<<N_GRAPHS, 128, 0, stream>>>(psum, pcnt, linW, linb, out);
}

// Round 2
// 1270.634 us; speedup vs baseline: 1.4712x; 1.4712x over previous
//
#include <hip/hip_runtime.h>
#include <hip/hip_bf16.h>

#define N_NODES 50000
#define N_EDGES 400000
#define N_GRAPHS 64
#define HEADS 4
#define GAT_DIM 128
#define FDIM 512   // HEADS*GAT_DIM
#define NEG_SLOPE 0.2f

// ---------------- CSR build ----------------
__global__ void deg_kernel(const int* __restrict__ edst, int* __restrict__ deg) {
    int e = blockIdx.x * blockDim.x + threadIdx.x;
    if (e < N_EDGES) atomicAdd(&deg[edst[e]], 1);
}

// single block, 1024 threads: exclusive scan of deg[N_NODES] -> off[N_NODES+1]
__global__ __launch_bounds__(1024) void scan_kernel(const int* __restrict__ deg,
                                                    int* __restrict__ off) {
    __shared__ int part[1024];
    const int n = N_NODES;
    int t = threadIdx.x;
    int chunk = (n + 1023) / 1024;
    int base = t * chunk;
    int s = 0;
    for (int i = 0; i < chunk; i++) {
        int idx = base + i;
        if (idx < n) s += deg[idx];
    }
    part[t] = s;
    __syncthreads();
    for (int d = 1; d < 1024; d <<= 1) {
        int add = (t >= d) ? part[t - d] : 0;
        __syncthreads();
        part[t] += add;
        __syncthreads();
    }
    int run = part[t] - s;  // exclusive prefix of this thread's chunk
    for (int i = 0; i < chunk; i++) {
        int idx = base + i;
        if (idx < n) { off[idx] = run; run += deg[idx]; }
    }
    if (t == 0) off[n] = part[1023];
}

__global__ void fill_kernel(const int* __restrict__ esrc, const int* __restrict__ edst,
                            const int* __restrict__ off, int* __restrict__ cursor,
                            int* __restrict__ csr_src) {
    int e = blockIdx.x * blockDim.x + threadIdx.x;
    if (e >= N_EDGES) return;
    int d = edst[e];
    int pos = off[d] + atomicAdd(&cursor[d], 1);
    csr_src[pos] = esrc[e];
}

// ---------------- layer 0 node transform: x[N,3] @ W[3,512] + b (float4) ----------------
__global__ void xform0_kernel(const float* __restrict__ x,
                              const float* __restrict__ Wl, const float* __restrict__ bl,
                              const float* __restrict__ Wr, const float* __restrict__ br,
                              float* __restrict__ xl, float* __restrict__ xr) {
    int idx = blockIdx.x * blockDim.x + threadIdx.x;  // over N*128 float4 groups
    if (idx >= N_NODES * 128) return;
    int n = idx >> 7;
    int j = (idx & 127) * 4;
    float x0 = x[n * 3 + 0], x1 = x[n * 3 + 1], x2 = x[n * 3 + 2];
    float4 wl0 = *(const float4*)(Wl + j);
    float4 wl1 = *(const float4*)(Wl + 512 + j);
    float4 wl2 = *(const float4*)(Wl + 1024 + j);
    float4 b0  = *(const float4*)(bl + j);
    float4 o;
    o.x = fmaf(x0, wl0.x, fmaf(x1, wl1.x, fmaf(x2, wl2.x, b0.x)));
    o.y = fmaf(x0, wl0.y, fmaf(x1, wl1.y, fmaf(x2, wl2.y, b0.y)));
    o.z = fmaf(x0, wl0.z, fmaf(x1, wl1.z, fmaf(x2, wl2.z, b0.z)));
    o.w = fmaf(x0, wl0.w, fmaf(x1, wl1.w, fmaf(x2, wl2.w, b0.w)));
    *(float4*)(xl + (size_t)n * FDIM + j) = o;
    float4 wr0 = *(const float4*)(Wr + j);
    float4 wr1 = *(const float4*)(Wr + 512 + j);
    float4 wr2 = *(const float4*)(Wr + 1024 + j);
    float4 b1  = *(const float4*)(br + j);
    o.x = fmaf(x0, wr0.x, fmaf(x1, wr1.x, fmaf(x2, wr2.x, b1.x)));
    o.y = fmaf(x0, wr0.y, fmaf(x1, wr1.y, fmaf(x2, wr2.y, b1.y)));
    o.z = fmaf(x0, wr0.z, fmaf(x1, wr1.z, fmaf(x2, wr2.z, b1.z)));
    o.w = fmaf(x0, wr0.w, fmaf(x1, wr1.w, fmaf(x2, wr2.w, b1.w)));
    *(float4*)(xr + (size_t)n * FDIM + j) = o;
}

// ---------------- dual fp32 GEMM: xl = A@Wl+bl, xr = A@Wr+br; A[M,128], W[128,512] -------
// BM=128 rows, BN=64 cols per W, BK=32. 256 threads, microtile (4+4)x4 per W.
#define BM 128
#define BN 64
#define BK 32
#define APAD 132
#define BPAD 68
__global__ __launch_bounds__(256) void gemm_dual_kernel(const float* __restrict__ A,
                                                        const float* __restrict__ Wl,
                                                        const float* __restrict__ bl,
                                                        const float* __restrict__ Wr,
                                                        const float* __restrict__ br,
                                                        float* __restrict__ xl,
                                                        float* __restrict__ xr, int M) {
    __shared__ float As[BK][APAD];
    __shared__ float Bsl[BK][BPAD];
    __shared__ float Bsr[BK][BPAD];
    int bn = blockIdx.x * BN;
    int bm = blockIdx.y * BM;
    int tid = threadIdx.x;
    int tm = tid & 15, tn = tid >> 4;
    float accl[8][4] = {};
    float accr[8][4] = {};
    for (int k0 = 0; k0 < 128; k0 += BK) {
        // stage A tile: 128 rows x 32 k (transpose to As[k][m])
#pragma unroll
        for (int i = 0; i < 4; i++) {
            int id = tid * 4 + i;          // 0..1023
            int row = id >> 3;
            int c4 = (id & 7) * 4;
            float4 v = make_float4(0.f, 0.f, 0.f, 0.f);
            int gr = bm + row;
            if (gr < M) v = *(const float4*)(A + (size_t)gr * 128 + k0 + c4);
            As[c4 + 0][row] = v.x; As[c4 + 1][row] = v.y;
            As[c4 + 2][row] = v.z; As[c4 + 3][row] = v.w;
        }
        // stage W tiles: 32 k-rows x 64 cols each
#pragma unroll
        for (int i = 0; i < 2; i++) {
            int id = tid + 256 * i;        // 0..511
            int row = id >> 4;
            int c4 = (id & 15) * 4;
            *(float4*)&Bsl[row][c4] = *(const float4*)(Wl + (size_t)(k0 + row) * 512 + bn + c4);
            *(float4*)&Bsr[row][c4] = *(const float4*)(Wr + (size_t)(k0 + row) * 512 + bn + c4);
        }
        __syncthreads();
#pragma unroll 4
        for (int k = 0; k < BK; k++) {
            float4 alo = *(const float4*)&As[k][tm * 4];
            float4 ahi = *(const float4*)&As[k][64 + tm * 4];
            float4 vbl = *(const float4*)&Bsl[k][tn * 4];
            float4 vbr = *(const float4*)&Bsr[k][tn * 4];
            float av[8] = {alo.x, alo.y, alo.z, alo.w, ahi.x, ahi.y, ahi.z, ahi.w};
            float blv[4] = {vbl.x, vbl.y, vbl.z, vbl.w};
            float brv[4] = {vbr.x, vbr.y, vbr.z, vbr.w};
#pragma unroll
            for (int i = 0; i < 8; i++)
#pragma unroll
                for (int j = 0; j < 4; j++) {
                    accl[i][j] = fmaf(av[i], blv[j], accl[i][j]);
                    accr[i][j] = fmaf(av[i], brv[j], accr[i][j]);
                }
        }
        __syncthreads();
    }
    int gc = bn + tn * 4;
    float4 bll = *(const float4*)(bl + gc);
    float4 brr = *(const float4*)(br + gc);
#pragma unroll
    for (int i = 0; i < 8; i++) {
        int gr = bm + (i < 4 ? tm * 4 + i : 64 + tm * 4 + (i - 4));
        if (gr >= M) continue;
        float4 ol, orr;
        ol.x = accl[i][0] + bll.x; ol.y = accl[i][1] + bll.y;
        ol.z = accl[i][2] + bll.z; ol.w = accl[i][3] + bll.w;
        orr.x = accr[i][0] + brr.x; orr.y = accr[i][1] + brr.y;
        orr.z = accr[i][2] + brr.z; orr.w = accr[i][3] + brr.w;
        *(float4*)(xl + (size_t)gr * 512 + gc) = ol;
        *(float4*)(xr + (size_t)gr * 512 + gc) = orr;
    }
}

// ------- fused edge score + online softmax + aggregate + head-mean + bias + ELU ----------
// one block (256 thr) per dst node; wave h handles head h
__global__ __launch_bounds__(256) void fused_edge_kernel(const int* __restrict__ off,
                                                         const int* __restrict__ csr_src,
                                                         const float* __restrict__ xl,
                                                         const float* __restrict__ xr,
                                                         const float* __restrict__ att,
                                                         const float* __restrict__ bias,
                                                         float* __restrict__ hout) {
    int n = blockIdx.x;
    int tid = threadIdx.x;
    int h = tid >> 6;
    int lane = tid & 63;
    int s = off[n], e = off[n + 1];
    float2 xr2 = *(const float2*)(xr + (size_t)n * FDIM + h * 128 + lane * 2);
    float2 at2 = *(const float2*)(att + h * 128 + lane * 2);
    float mx = -1e30f;
    float denom = 0.f;
    float2 acc = make_float2(0.f, 0.f);
    int src = (s < e) ? csr_src[s] : 0;
    for (int p = s; p < e; p++) {
        int nxt = (p + 1 < e) ? csr_src[p + 1] : 0;
        float2 v = *(const float2*)(xl + (size_t)src * FDIM + h * 128 + lane * 2);
        float m0 = v.x + xr2.x, m1 = v.y + xr2.y;
        m0 = m0 > 0.f ? m0 : NEG_SLOPE * m0;
        m1 = m1 > 0.f ? m1 : NEG_SLOPE * m1;
        float part = fmaf(m0, at2.x, m1 * at2.y);
        part += __shfl_xor(part, 1);
        part += __shfl_xor(part, 2);
        part += __shfl_xor(part, 4);
        part += __shfl_xor(part, 8);
        part += __shfl_xor(part, 16);
        part += __shfl_xor(part, 32);
        // online softmax update (part is wave-uniform)
        float mnew = fmaxf(mx, part);
        float scale = expf(mx - mnew);
        float w = expf(part - mnew);
        denom = fmaf(denom, scale, w);
        acc.x = fmaf(acc.x, scale, w * v.x);
        acc.y = fmaf(acc.y, scale, w * v.y);
        mx = mnew;
        src = nxt;
    }
    float inv = denom > 0.f ? 1.f / denom : 0.f;
    acc.x *= inv; acc.y *= inv;
    __shared__ float sh[4][128];
    sh[h][lane * 2 + 0] = acc.x;
    sh[h][lane * 2 + 1] = acc.y;
    __syncthreads();
    if (tid < 128) {
        float v = 0.25f * (sh[0][tid] + sh[1][tid] + sh[2][tid] + sh[3][tid]) + bias[tid];
        v = v > 0.f ? v : (expf(v) - 1.f);  // ELU
        hout[(size_t)n * GAT_DIM + tid] = v;
    }
}

// ---------------- mean pool over sorted batch (double accumulation) ----------------
#define POOL_CHUNK 512
__global__ __launch_bounds__(128) void pool_kernel(const float* __restrict__ h,
                                                   const int* __restrict__ batch,
                                                   double* __restrict__ psum,
                                                   int* __restrict__ pcnt) {
    int c = threadIdx.x;  // 0..127
    int n0 = blockIdx.x * POOL_CHUNK;
    int n1 = min(n0 + POOL_CHUNK, N_NODES);
    if (n0 >= N_NODES) return;
    double acc = 0.0;
    int cur = batch[n0];
    int cnt = 0;
    for (int n = n0; n < n1; n++) {
        int g = batch[n];
        if (g != cur) {
            atomicAdd(&psum[(size_t)cur * GAT_DIM + c], acc);
            if (c == 0) atomicAdd(&pcnt[cur], cnt);
            acc = 0.0; cnt = 0; cur = g;
        }
        acc += (double)h[(size_t)n * GAT_DIM + c];
        cnt++;
    }
    atomicAdd(&psum[(size_t)cur * GAT_DIM + c], acc);
    if (c == 0) atomicAdd(&pcnt[cur], cnt);
}

// ---------------- final linear: out[64,128] = g @ linW + linb ----------------
__global__ __launch_bounds__(128) void final_kernel(const double* __restrict__ psum,
                                                    const int* __restrict__ pcnt,
                                                    const float* __restrict__ linW,
                                                    const float* __restrict__ linb,
                                                    float* __restrict__ out) {
    int g = blockIdx.x;       // 0..63
    int j = threadIdx.x;      // 0..127
    __shared__ float gv[128];
    float cnt = (float)max(pcnt[g], 1);
    gv[j] = (float)(psum[(size_t)g * 128 + j] / (double)cnt);
    __syncthreads();
    float acc = 0.f;
    for (int c = 0; c < 128; c++) acc = fmaf(gv[c], linW[c * 128 + j], acc);
    out[(size_t)g * 128 + j] = acc + linb[j];
}

extern "C" void kernel_launch(void* const* d_in, const int* in_sizes, int n_in,
                              void* d_out, int out_size, void* d_ws, size_t ws_size,
                              hipStream_t stream) {
    const float* x    = (const float*)d_in[0];
    const int* eidx   = (const int*)d_in[1];
    const int* batch  = (const int*)d_in[2];
    const float* Wl[3] = {(const float*)d_in[3],  (const float*)d_in[9],  (const float*)d_in[15]};
    const float* bl[3] = {(const float*)d_in[4],  (const float*)d_in[10], (const float*)d_in[16]};
    const float* Wr[3] = {(const float*)d_in[5],  (const float*)d_in[11], (const float*)d_in[17]};
    const float* br[3] = {(const float*)d_in[6],  (const float*)d_in[12], (const float*)d_in[18]};
    const float* att[3] = {(const float*)d_in[7], (const float*)d_in[13], (const float*)d_in[19]};
    const float* bb[3] = {(const float*)d_in[8],  (const float*)d_in[14], (const float*)d_in[20]};
    const float* linW = (const float*)d_in[21];
    const float* linb = (const float*)d_in[22];
    float* out = (float*)d_out;

    const int* esrc = eidx;
    const int* edst = eidx + N_EDGES;

    // workspace carve-up (256B aligned)
    char* p = (char*)d_ws;
    auto alloc = [&](size_t bytes) { void* r = (void*)p; p += (bytes + 255) & ~(size_t)255; return r; };
    float* xl      = (float*)alloc((size_t)N_NODES * FDIM * 4);   // 102.4 MB
    float* xr      = (float*)alloc((size_t)N_NODES * FDIM * 4);   // 102.4 MB
    float* hbuf    = (float*)alloc((size_t)N_NODES * GAT_DIM * 4);// 25.6 MB
    int*   deg     = (int*)alloc((size_t)N_NODES * 4);
    int*   off     = (int*)alloc((size_t)(N_NODES + 1) * 4);
    int*   cursor  = (int*)alloc((size_t)N_NODES * 4);
    int*   csr_src = (int*)alloc((size_t)N_EDGES * 4);
    double* psum   = (double*)alloc((size_t)N_GRAPHS * GAT_DIM * 8);
    int*   pcnt    = (int*)alloc((size_t)N_GRAPHS * 4);

    hipMemsetAsync(deg, 0, (size_t)N_NODES * 4, stream);
    hipMemsetAsync(cursor, 0, (size_t)N_NODES * 4, stream);
    hipMemsetAsync(psum, 0, (size_t)N_GRAPHS * GAT_DIM * 8, stream);
    hipMemsetAsync(pcnt, 0, (size_t)N_GRAPHS * 4, stream);

    // CSR build (dst is layer-invariant)
    deg_kernel<<<(N_EDGES + 255) / 256, 256, 0, stream>>>(edst, deg);
    scan_kernel<<<1, 1024, 0, stream>>>(deg, off);
    fill_kernel<<<(N_EDGES + 255) / 256, 256, 0, stream>>>(esrc, edst, off, cursor, csr_src);

    dim3 ggrid(512 / BN, (N_NODES + BM - 1) / BM);

    for (int l = 0; l < 3; l++) {
        if (l == 0) {
            xform0_kernel<<<(N_NODES * 128 + 255) / 256, 256, 0, stream>>>(
                x, Wl[0], bl[0], Wr[0], br[0], xl, xr);
        } else {
            gemm_dual_kernel<<<ggrid, 256, 0, stream>>>(hbuf, Wl[l], bl[l], Wr[l], br[l],
                                                        xl, xr, N_NODES);
        }
        fused_edge_kernel<<<N_NODES, 256, 0, stream>>>(off, csr_src, xl, xr, att[l], bb[l], hbuf);
    }

    pool_kernel<<<(N_NODES + POOL_CHUNK - 1) / POOL_CHUNK, 128, 0, stream>>>(hbuf, batch, psum, pcnt);
    final_kernel<<<N_GRAPHS, 128, 0, stream>>>(psum, pcnt, linW, linb, out);
}

// Round 3
// 1129.925 us; speedup vs baseline: 1.6544x; 1.1245x over previous
//
#include <hip/hip_runtime.h>
#include <hip/hip_bf16.h>

#define N_NODES 50000
#define N_EDGES 400000
#define N_GRAPHS 64
#define HEADS 4
#define GAT_DIM 128
#define FDIM 512   // HEADS*GAT_DIM
#define NEG_SLOPE 0.2f

// ---------------- CSR build ----------------
__global__ void deg_kernel(const int* __restrict__ edst, int* __restrict__ deg) {
    int e = blockIdx.x * blockDim.x + threadIdx.x;
    if (e < N_EDGES) atomicAdd(&deg[edst[e]], 1);
}

// single block, 1024 threads: exclusive scan of deg[N_NODES] -> off[N_NODES+1]
__global__ __launch_bounds__(1024) void scan_kernel(const int* __restrict__ deg,
                                                    int* __restrict__ off) {
    __shared__ int part[1024];
    const int n = N_NODES;
    int t = threadIdx.x;
    int chunk = (n + 1023) / 1024;
    int base = t * chunk;
    int s = 0;
    for (int i = 0; i < chunk; i++) {
        int idx = base + i;
        if (idx < n) s += deg[idx];
    }
    part[t] = s;
    __syncthreads();
    for (int d = 1; d < 1024; d <<= 1) {
        int add = (t >= d) ? part[t - d] : 0;
        __syncthreads();
        part[t] += add;
        __syncthreads();
    }
    int run = part[t] - s;  // exclusive prefix of this thread's chunk
    for (int i = 0; i < chunk; i++) {
        int idx = base + i;
        if (idx < n) { off[idx] = run; run += deg[idx]; }
    }
    if (t == 0) off[n] = part[1023];
}

__global__ void fill_kernel(const int* __restrict__ esrc, const int* __restrict__ edst,
                            const int* __restrict__ off, int* __restrict__ cursor,
                            int* __restrict__ csr_src) {
    int e = blockIdx.x * blockDim.x + threadIdx.x;
    if (e >= N_EDGES) return;
    int d = edst[e];
    int pos = off[d] + atomicAdd(&cursor[d], 1);
    csr_src[pos] = esrc[e];
}

// ---------------- layer 0 node transform: x[N,3] @ W[3,512] + b (float4) ----------------
__global__ void xform0_kernel(const float* __restrict__ x,
                              const float* __restrict__ Wl, const float* __restrict__ bl,
                              const float* __restrict__ Wr, const float* __restrict__ br,
                              float* __restrict__ xl, float* __restrict__ xr) {
    int idx = blockIdx.x * blockDim.x + threadIdx.x;  // over N*128 float4 groups
    if (idx >= N_NODES * 128) return;
    int n = idx >> 7;
    int j = (idx & 127) * 4;
    float x0 = x[n * 3 + 0], x1 = x[n * 3 + 1], x2 = x[n * 3 + 2];
    float4 wl0 = *(const float4*)(Wl + j);
    float4 wl1 = *(const float4*)(Wl + 512 + j);
    float4 wl2 = *(const float4*)(Wl + 1024 + j);
    float4 b0  = *(const float4*)(bl + j);
    float4 o;
    o.x = fmaf(x0, wl0.x, fmaf(x1, wl1.x, fmaf(x2, wl2.x, b0.x)));
    o.y = fmaf(x0, wl0.y, fmaf(x1, wl1.y, fmaf(x2, wl2.y, b0.y)));
    o.z = fmaf(x0, wl0.z, fmaf(x1, wl1.z, fmaf(x2, wl2.z, b0.z)));
    o.w = fmaf(x0, wl0.w, fmaf(x1, wl1.w, fmaf(x2, wl2.w, b0.w)));
    *(float4*)(xl + (size_t)n * FDIM + j) = o;
    float4 wr0 = *(const float4*)(Wr + j);
    float4 wr1 = *(const float4*)(Wr + 512 + j);
    float4 wr2 = *(const float4*)(Wr + 1024 + j);
    float4 b1  = *(const float4*)(br + j);
    o.x = fmaf(x0, wr0.x, fmaf(x1, wr1.x, fmaf(x2, wr2.x, b1.x)));
    o.y = fmaf(x0, wr0.y, fmaf(x1, wr1.y, fmaf(x2, wr2.y, b1.y)));
    o.z = fmaf(x0, wr0.z, fmaf(x1, wr1.z, fmaf(x2, wr2.z, b1.z)));
    o.w = fmaf(x0, wr0.w, fmaf(x1, wr1.w, fmaf(x2, wr2.w, b1.w)));
    *(float4*)(xr + (size_t)n * FDIM + j) = o;
}

// ---------------- dual fp32 GEMM (double-buffered): xl=A@Wl+bl, xr=A@Wr+br ----------------
#define BM 128
#define BN 64
#define BK 32
#define APAD 132
#define BPAD 68
__global__ __launch_bounds__(256) void gemm_dual_kernel(const float* __restrict__ A,
                                                        const float* __restrict__ Wl,
                                                        const float* __restrict__ bl,
                                                        const float* __restrict__ Wr,
                                                        const float* __restrict__ br,
                                                        float* __restrict__ xl,
                                                        float* __restrict__ xr, int M) {
    __shared__ float As[2][BK][APAD];
    __shared__ float Bsl[2][BK][BPAD];
    __shared__ float Bsr[2][BK][BPAD];
    int bn = blockIdx.x * BN;
    int bm = blockIdx.y * BM;
    int tid = threadIdx.x;
    int tm = tid & 15, tn = tid >> 4;
    float accl[8][4] = {};
    float accr[8][4] = {};

    // per-thread staging coordinates
    const int arow[4] = {(tid * 4 + 0) >> 3, (tid * 4 + 1) >> 3, (tid * 4 + 2) >> 3, (tid * 4 + 3) >> 3};
    const int ac4[4]  = {((tid * 4 + 0) & 7) * 4, ((tid * 4 + 1) & 7) * 4, ((tid * 4 + 2) & 7) * 4, ((tid * 4 + 3) & 7) * 4};
    const int brow[2] = {tid >> 4, (tid + 256) >> 4};
    const int bc4[2]  = {(tid & 15) * 4, ((tid + 256) & 15) * 4};

    float4 pa[4], pbl[2], pbr[2];

    // ---- load stage 0 ----
#pragma unroll
    for (int i = 0; i < 4; i++) {
        int gr = bm + arow[i];
        pa[i] = (gr < M) ? *(const float4*)(A + (size_t)gr * 128 + 0 + ac4[i])
                         : make_float4(0.f, 0.f, 0.f, 0.f);
    }
#pragma unroll
    for (int i = 0; i < 2; i++) {
        pbl[i] = *(const float4*)(Wl + (size_t)(0 + brow[i]) * 512 + bn + bc4[i]);
        pbr[i] = *(const float4*)(Wr + (size_t)(0 + brow[i]) * 512 + bn + bc4[i]);
    }
#pragma unroll
    for (int i = 0; i < 4; i++) {
        As[0][ac4[i] + 0][arow[i]] = pa[i].x; As[0][ac4[i] + 1][arow[i]] = pa[i].y;
        As[0][ac4[i] + 2][arow[i]] = pa[i].z; As[0][ac4[i] + 3][arow[i]] = pa[i].w;
    }
#pragma unroll
    for (int i = 0; i < 2; i++) {
        *(float4*)&Bsl[0][brow[i]][bc4[i]] = pbl[i];
        *(float4*)&Bsr[0][brow[i]][bc4[i]] = pbr[i];
    }
    __syncthreads();

    for (int s = 0; s < 4; s++) {
        int cur = s & 1;
        if (s < 3) {
            int k0 = (s + 1) * BK;
#pragma unroll
            for (int i = 0; i < 4; i++) {
                int gr = bm + arow[i];
                pa[i] = (gr < M) ? *(const float4*)(A + (size_t)gr * 128 + k0 + ac4[i])
                                 : make_float4(0.f, 0.f, 0.f, 0.f);
            }
#pragma unroll
            for (int i = 0; i < 2; i++) {
                pbl[i] = *(const float4*)(Wl + (size_t)(k0 + brow[i]) * 512 + bn + bc4[i]);
                pbr[i] = *(const float4*)(Wr + (size_t)(k0 + brow[i]) * 512 + bn + bc4[i]);
            }
        }
#pragma unroll 4
        for (int k = 0; k < BK; k++) {
            float4 alo = *(const float4*)&As[cur][k][tm * 4];
            float4 ahi = *(const float4*)&As[cur][k][64 + tm * 4];
            float4 vbl = *(const float4*)&Bsl[cur][k][tn * 4];
            float4 vbr = *(const float4*)&Bsr[cur][k][tn * 4];
            float av[8] = {alo.x, alo.y, alo.z, alo.w, ahi.x, ahi.y, ahi.z, ahi.w};
            float blv[4] = {vbl.x, vbl.y, vbl.z, vbl.w};
            float brv[4] = {vbr.x, vbr.y, vbr.z, vbr.w};
#pragma unroll
            for (int i = 0; i < 8; i++)
#pragma unroll
                for (int j = 0; j < 4; j++) {
                    accl[i][j] = fmaf(av[i], blv[j], accl[i][j]);
                    accr[i][j] = fmaf(av[i], brv[j], accr[i][j]);
                }
        }
        if (s < 3) {
            int nb = cur ^ 1;
#pragma unroll
            for (int i = 0; i < 4; i++) {
                As[nb][ac4[i] + 0][arow[i]] = pa[i].x; As[nb][ac4[i] + 1][arow[i]] = pa[i].y;
                As[nb][ac4[i] + 2][arow[i]] = pa[i].z; As[nb][ac4[i] + 3][arow[i]] = pa[i].w;
            }
#pragma unroll
            for (int i = 0; i < 2; i++) {
                *(float4*)&Bsl[nb][brow[i]][bc4[i]] = pbl[i];
                *(float4*)&Bsr[nb][brow[i]][bc4[i]] = pbr[i];
            }
            __syncthreads();
        }
    }

    int gc = bn + tn * 4;
    float4 bll = *(const float4*)(bl + gc);
    float4 brr = *(const float4*)(br + gc);
#pragma unroll
    for (int i = 0; i < 8; i++) {
        int gr = bm + (i < 4 ? tm * 4 + i : 64 + tm * 4 + (i - 4));
        if (gr >= M) continue;
        float4 ol, orr;
        ol.x = accl[i][0] + bll.x; ol.y = accl[i][1] + bll.y;
        ol.z = accl[i][2] + bll.z; ol.w = accl[i][3] + bll.w;
        orr.x = accr[i][0] + brr.x; orr.y = accr[i][1] + brr.y;
        orr.z = accr[i][2] + brr.z; orr.w = accr[i][3] + brr.w;
        *(float4*)(xl + (size_t)gr * 512 + gc) = ol;
        *(float4*)(xr + (size_t)gr * 512 + gc) = orr;
    }
}

// ------- fused edge score + online softmax + aggregate + head-mean + bias + ELU ----------
// ONE WAVE PER NODE, all 4 heads simultaneously. lane = h*16+q owns channels lane*8..lane*8+7
__global__ __launch_bounds__(256) void fused_edge_kernel(const int* __restrict__ off,
                                                         const int* __restrict__ csr_src,
                                                         const float* __restrict__ xl,
                                                         const float* __restrict__ xr,
                                                         const float* __restrict__ att,
                                                         const float* __restrict__ bias,
                                                         float* __restrict__ hout) {
    int wid = threadIdx.x >> 6;
    int lane = threadIdx.x & 63;
    int n = blockIdx.x * 4 + wid;
    if (n >= N_NODES) return;
    int s = off[n], e = off[n + 1];
    const int loff = lane * 8;  // = h*128 + q*8
    float4 xr0 = *(const float4*)(xr + (size_t)n * FDIM + loff);
    float4 xr1 = *(const float4*)(xr + (size_t)n * FDIM + loff + 4);
    float4 at0 = *(const float4*)(att + loff);
    float4 at1 = *(const float4*)(att + loff + 4);

    float mx = -1e30f, denom = 0.f;
    float a0 = 0.f, a1 = 0.f, a2 = 0.f, a3 = 0.f, a4 = 0.f, a5 = 0.f, a6 = 0.f, a7 = 0.f;

    float4 v0, v1;
    if (s < e) {
        int src = csr_src[s];
        const float* b = xl + (size_t)src * FDIM + loff;
        v0 = *(const float4*)b; v1 = *(const float4*)(b + 4);
    }
    for (int p = s; p < e; p++) {
        float4 n0, n1;
        if (p + 1 < e) {
            int nxt = csr_src[p + 1];
            const float* b = xl + (size_t)nxt * FDIM + loff;
            n0 = *(const float4*)b; n1 = *(const float4*)(b + 4);
        }
#define LK(mm) fmaf(fminf(mm, 0.f), NEG_SLOPE, fmaxf(mm, 0.f))
        float part;
        part = LK(v0.x + xr0.x) * at0.x;
        part = fmaf(LK(v0.y + xr0.y), at0.y, part);
        part = fmaf(LK(v0.z + xr0.z), at0.z, part);
        part = fmaf(LK(v0.w + xr0.w), at0.w, part);
        part = fmaf(LK(v1.x + xr1.x), at1.x, part);
        part = fmaf(LK(v1.y + xr1.y), at1.y, part);
        part = fmaf(LK(v1.z + xr1.z), at1.z, part);
        part = fmaf(LK(v1.w + xr1.w), at1.w, part);
#undef LK
        // reduce within each 16-lane head group
        part += __shfl_xor(part, 1);
        part += __shfl_xor(part, 2);
        part += __shfl_xor(part, 4);
        part += __shfl_xor(part, 8);
        // online softmax (part uniform within head group)
        float mnew = fmaxf(mx, part);
        float scale = __expf(mx - mnew);
        float w = __expf(part - mnew);
        denom = fmaf(denom, scale, w);
        a0 = fmaf(a0, scale, w * v0.x);
        a1 = fmaf(a1, scale, w * v0.y);
        a2 = fmaf(a2, scale, w * v0.z);
        a3 = fmaf(a3, scale, w * v0.w);
        a4 = fmaf(a4, scale, w * v1.x);
        a5 = fmaf(a5, scale, w * v1.y);
        a6 = fmaf(a6, scale, w * v1.z);
        a7 = fmaf(a7, scale, w * v1.w);
        mx = mnew;
        v0 = n0; v1 = n1;
    }
    float inv = denom > 0.f ? 1.f / denom : 0.f;
    a0 *= inv; a1 *= inv; a2 *= inv; a3 *= inv;
    a4 *= inv; a5 *= inv; a6 *= inv; a7 *= inv;
    // head mean: sum over the 4 head groups (lane bits 4,5)
    a0 += __shfl_xor(a0, 16); a0 += __shfl_xor(a0, 32);
    a1 += __shfl_xor(a1, 16); a1 += __shfl_xor(a1, 32);
    a2 += __shfl_xor(a2, 16); a2 += __shfl_xor(a2, 32);
    a3 += __shfl_xor(a3, 16); a3 += __shfl_xor(a3, 32);
    a4 += __shfl_xor(a4, 16); a4 += __shfl_xor(a4, 32);
    a5 += __shfl_xor(a5, 16); a5 += __shfl_xor(a5, 32);
    a6 += __shfl_xor(a6, 16); a6 += __shfl_xor(a6, 32);
    a7 += __shfl_xor(a7, 16); a7 += __shfl_xor(a7, 32);
    if (lane < 16) {
        float4 b0 = *(const float4*)(bias + lane * 8);
        float4 b1 = *(const float4*)(bias + lane * 8 + 4);
        float o[8];
        o[0] = fmaf(0.25f, a0, b0.x); o[1] = fmaf(0.25f, a1, b0.y);
        o[2] = fmaf(0.25f, a2, b0.z); o[3] = fmaf(0.25f, a3, b0.w);
        o[4] = fmaf(0.25f, a4, b1.x); o[5] = fmaf(0.25f, a5, b1.y);
        o[6] = fmaf(0.25f, a6, b1.z); o[7] = fmaf(0.25f, a7, b1.w);
#pragma unroll
        for (int j = 0; j < 8; j++) o[j] = o[j] > 0.f ? o[j] : (__expf(o[j]) - 1.f);
        float4 s0 = make_float4(o[0], o[1], o[2], o[3]);
        float4 s1 = make_float4(o[4], o[5], o[6], o[7]);
        *(float4*)(hout + (size_t)n * GAT_DIM + lane * 8) = s0;
        *(float4*)(hout + (size_t)n * GAT_DIM + lane * 8 + 4) = s1;
    }
}

// ---------------- mean pool over sorted batch (double accumulation) ----------------
#define POOL_CHUNK 512
__global__ __launch_bounds__(128) void pool_kernel(const float* __restrict__ h,
                                                   const int* __restrict__ batch,
                                                   double* __restrict__ psum,
                                                   int* __restrict__ pcnt) {
    int c = threadIdx.x;  // 0..127
    int n0 = blockIdx.x * POOL_CHUNK;
    int n1 = min(n0 + POOL_CHUNK, N_NODES);
    if (n0 >= N_NODES) return;
    double acc = 0.0;
    int cur = batch[n0];
    int cnt = 0;
    for (int n = n0; n < n1; n++) {
        int g = batch[n];
        if (g != cur) {
            atomicAdd(&psum[(size_t)cur * GAT_DIM + c], acc);
            if (c == 0) atomicAdd(&pcnt[cur], cnt);
            acc = 0.0; cnt = 0; cur = g;
        }
        acc += (double)h[(size_t)n * GAT_DIM + c];
        cnt++;
    }
    atomicAdd(&psum[(size_t)cur * GAT_DIM + c], acc);
    if (c == 0) atomicAdd(&pcnt[cur], cnt);
}

// ---------------- final linear: out[64,128] = g @ linW + linb ----------------
__global__ __launch_bounds__(128) void final_kernel(const double* __restrict__ psum,
                                                    const int* __restrict__ pcnt,
                                                    const float* __restrict__ linW,
                                                    const float* __restrict__ linb,
                                                    float* __restrict__ out) {
    int g = blockIdx.x;       // 0..63
    int j = threadIdx.x;      // 0..127
    __shared__ float gv[128];
    float cnt = (float)max(pcnt[g], 1);
    gv[j] = (float)(psum[(size_t)g * 128 + j] / (double)cnt);
    __syncthreads();
    float acc = 0.f;
    for (int c = 0; c < 128; c++) acc = fmaf(gv[c], linW[c * 128 + j], acc);
    out[(size_t)g * 128 + j] = acc + linb[j];
}

extern "C" void kernel_launch(void* const* d_in, const int* in_sizes, int n_in,
                              void* d_out, int out_size, void* d_ws, size_t ws_size,
                              hipStream_t stream) {
    const float* x    = (const float*)d_in[0];
    const int* eidx   = (const int*)d_in[1];
    const int* batch  = (const int*)d_in[2];
    const float* Wl[3] = {(const float*)d_in[3],  (const float*)d_in[9],  (const float*)d_in[15]};
    const float* bl[3] = {(const float*)d_in[4],  (const float*)d_in[10], (const float*)d_in[16]};
    const float* Wr[3] = {(const float*)d_in[5],  (const float*)d_in[11], (const float*)d_in[17]};
    const float* br[3] = {(const float*)d_in[6],  (const float*)d_in[12], (const float*)d_in[18]};
    const float* att[3] = {(const float*)d_in[7], (const float*)d_in[13], (const float*)d_in[19]};
    const float* bb[3] = {(const float*)d_in[8],  (const float*)d_in[14], (const float*)d_in[20]};
    const float* linW = (const float*)d_in[21];
    const float* linb = (const float*)d_in[22];
    float* out = (float*)d_out;

    const int* esrc = eidx;
    const int* edst = eidx + N_EDGES;

    // workspace carve-up (256B aligned)
    char* p = (char*)d_ws;
    auto alloc = [&](size_t bytes) { void* r = (void*)p; p += (bytes + 255) & ~(size_t)255; return r; };
    float* xl      = (float*)alloc((size_t)N_NODES * FDIM * 4);   // 102.4 MB
    float* xr      = (float*)alloc((size_t)N_NODES * FDIM * 4);   // 102.4 MB
    float* hbuf    = (float*)alloc((size_t)N_NODES * GAT_DIM * 4);// 25.6 MB
    int*   deg     = (int*)alloc((size_t)N_NODES * 4);
    int*   off     = (int*)alloc((size_t)(N_NODES + 1) * 4);
    int*   cursor  = (int*)alloc((size_t)N_NODES * 4);
    int*   csr_src = (int*)alloc((size_t)N_EDGES * 4);
    double* psum   = (double*)alloc((size_t)N_GRAPHS * GAT_DIM * 8);
    int*   pcnt    = (int*)alloc((size_t)N_GRAPHS * 4);

    hipMemsetAsync(deg, 0, (size_t)N_NODES * 4, stream);
    hipMemsetAsync(cursor, 0, (size_t)N_NODES * 4, stream);
    hipMemsetAsync(psum, 0, (size_t)N_GRAPHS * GAT_DIM * 8, stream);
    hipMemsetAsync(pcnt, 0, (size_t)N_GRAPHS * 4, stream);

    // CSR build (dst is layer-invariant)
    deg_kernel<<<(N_EDGES + 255) / 256, 256, 0, stream>>>(edst, deg);
    scan_kernel<<<1, 1024, 0, stream>>>(deg, off);
    fill_kernel<<<(N_EDGES + 255) / 256, 256, 0, stream>>>(esrc, edst, off, cursor, csr_src);

    dim3 ggrid(512 / BN, (N_NODES + BM - 1) / BM);
    const int egrid = (N_NODES + 3) / 4;  // 4 nodes (waves) per 256-thr block

    for (int l = 0; l < 3; l++) {
        if (l == 0) {
            xform0_kernel<<<(N_NODES * 128 + 255) / 256, 256, 0, stream>>>(
                x, Wl[0], bl[0], Wr[0], br[0], xl, xr);
        } else {
            gemm_dual_kernel<<<ggrid, 256, 0, stream>>>(hbuf, Wl[l], bl[l], Wr[l], br[l],
                                                        xl, xr, N_NODES);
        }
        fused_edge_kernel<<<egrid, 256, 0, stream>>>(off, csr_src, xl, xr, att[l], bb[l], hbuf);
    }

    pool_kernel<<<(N_NODES + POOL_CHUNK - 1) / POOL_CHUNK, 128, 0, stream>>>(hbuf, batch, psum, pcnt);
    final_kernel<<<N_GRAPHS, 128, 0, stream>>>(psum, pcnt, linW, linb, out);
}

// Round 4
// 976.601 us; speedup vs baseline: 1.9141x; 1.1570x over previous
//
#include <hip/hip_runtime.h>
#include <hip/hip_bf16.h>

#define N_NODES 50000
#define N_EDGES 400000
#define N_GRAPHS 64
#define HEADS 4
#define GAT_DIM 128
#define FDIM 512   // HEADS*GAT_DIM
#define NEG_SLOPE 0.2f

// ---------------- CSR build ----------------
__global__ void deg_kernel(const int* __restrict__ edst, int* __restrict__ deg) {
    int e = blockIdx.x * blockDim.x + threadIdx.x;
    if (e < N_EDGES) atomicAdd(&deg[edst[e]], 1);
}

// single block, 1024 threads: exclusive scan of deg[N_NODES] -> off[N_NODES+1]
__global__ __launch_bounds__(1024) void scan_kernel(const int* __restrict__ deg,
                                                    int* __restrict__ off) {
    __shared__ int part[1024];
    const int n = N_NODES;
    int t = threadIdx.x;
    int chunk = (n + 1023) / 1024;
    int base = t * chunk;
    int s = 0;
    for (int i = 0; i < chunk; i++) {
        int idx = base + i;
        if (idx < n) s += deg[idx];
    }
    part[t] = s;
    __syncthreads();
    for (int d = 1; d < 1024; d <<= 1) {
        int add = (t >= d) ? part[t - d] : 0;
        __syncthreads();
        part[t] += add;
        __syncthreads();
    }
    int run = part[t] - s;  // exclusive prefix of this thread's chunk
    for (int i = 0; i < chunk; i++) {
        int idx = base + i;
        if (idx < n) { off[idx] = run; run += deg[idx]; }
    }
    if (t == 0) off[n] = part[1023];
}

__global__ void fill_kernel(const int* __restrict__ esrc, const int* __restrict__ edst,
                            const int* __restrict__ off, int* __restrict__ cursor,
                            int* __restrict__ csr_src) {
    int e = blockIdx.x * blockDim.x + threadIdx.x;
    if (e >= N_EDGES) return;
    int d = edst[e];
    int pos = off[d] + atomicAdd(&cursor[d], 1);
    csr_src[pos] = esrc[e];
}

// ---------------- dual fp32 GEMM (single-buffer LDS + reg prefetch) ----------------
#define BM 128
#define BN 64
#define BK 32
#define APAD 132
#define BPAD 68
__global__ __launch_bounds__(256, 4) void gemm_dual_kernel(const float* __restrict__ A,
                                                           const float* __restrict__ Wl,
                                                           const float* __restrict__ bl,
                                                           const float* __restrict__ Wr,
                                                           const float* __restrict__ br,
                                                           float* __restrict__ xl,
                                                           float* __restrict__ xr, int M) {
    __shared__ float As[BK][APAD];
    __shared__ float Bsl[BK][BPAD];
    __shared__ float Bsr[BK][BPAD];
    int bn = blockIdx.x * BN;
    int bm = blockIdx.y * BM;
    int tid = threadIdx.x;
    int tm = tid & 15, tn = tid >> 4;
    float accl[8][4] = {};
    float accr[8][4] = {};

    const int arow[4] = {(tid * 4 + 0) >> 3, (tid * 4 + 1) >> 3, (tid * 4 + 2) >> 3, (tid * 4 + 3) >> 3};
    const int ac4[4]  = {((tid * 4 + 0) & 7) * 4, ((tid * 4 + 1) & 7) * 4, ((tid * 4 + 2) & 7) * 4, ((tid * 4 + 3) & 7) * 4};
    const int brow[2] = {tid >> 4, (tid + 256) >> 4};
    const int bc4[2]  = {(tid & 15) * 4, ((tid + 256) & 15) * 4};

    float4 pa[4], pbl[2], pbr[2];

    // ---- load + stage 0 ----
#pragma unroll
    for (int i = 0; i < 4; i++) {
        int gr = bm + arow[i];
        pa[i] = (gr < M) ? *(const float4*)(A + (size_t)gr * 128 + 0 + ac4[i])
                         : make_float4(0.f, 0.f, 0.f, 0.f);
    }
#pragma unroll
    for (int i = 0; i < 2; i++) {
        pbl[i] = *(const float4*)(Wl + (size_t)(0 + brow[i]) * 512 + bn + bc4[i]);
        pbr[i] = *(const float4*)(Wr + (size_t)(0 + brow[i]) * 512 + bn + bc4[i]);
    }
#pragma unroll
    for (int i = 0; i < 4; i++) {
        As[ac4[i] + 0][arow[i]] = pa[i].x; As[ac4[i] + 1][arow[i]] = pa[i].y;
        As[ac4[i] + 2][arow[i]] = pa[i].z; As[ac4[i] + 3][arow[i]] = pa[i].w;
    }
#pragma unroll
    for (int i = 0; i < 2; i++) {
        *(float4*)&Bsl[brow[i]][bc4[i]] = pbl[i];
        *(float4*)&Bsr[brow[i]][bc4[i]] = pbr[i];
    }
    __syncthreads();

    for (int s = 0; s < 4; s++) {
        if (s < 3) {  // prefetch next stage into registers
            int k0 = (s + 1) * BK;
#pragma unroll
            for (int i = 0; i < 4; i++) {
                int gr = bm + arow[i];
                pa[i] = (gr < M) ? *(const float4*)(A + (size_t)gr * 128 + k0 + ac4[i])
                                 : make_float4(0.f, 0.f, 0.f, 0.f);
            }
#pragma unroll
            for (int i = 0; i < 2; i++) {
                pbl[i] = *(const float4*)(Wl + (size_t)(k0 + brow[i]) * 512 + bn + bc4[i]);
                pbr[i] = *(const float4*)(Wr + (size_t)(k0 + brow[i]) * 512 + bn + bc4[i]);
            }
        }
#pragma unroll 4
        for (int k = 0; k < BK; k++) {
            float4 alo = *(const float4*)&As[k][tm * 4];
            float4 ahi = *(const float4*)&As[k][64 + tm * 4];
            float4 vbl = *(const float4*)&Bsl[k][tn * 4];
            float4 vbr = *(const float4*)&Bsr[k][tn * 4];
            float av[8] = {alo.x, alo.y, alo.z, alo.w, ahi.x, ahi.y, ahi.z, ahi.w};
            float blv[4] = {vbl.x, vbl.y, vbl.z, vbl.w};
            float brv[4] = {vbr.x, vbr.y, vbr.z, vbr.w};
#pragma unroll
            for (int i = 0; i < 8; i++)
#pragma unroll
                for (int j = 0; j < 4; j++) {
                    accl[i][j] = fmaf(av[i], blv[j], accl[i][j]);
                    accr[i][j] = fmaf(av[i], brv[j], accr[i][j]);
                }
        }
        if (s < 3) {
            __syncthreads();  // everyone done reading current stage
#pragma unroll
            for (int i = 0; i < 4; i++) {
                As[ac4[i] + 0][arow[i]] = pa[i].x; As[ac4[i] + 1][arow[i]] = pa[i].y;
                As[ac4[i] + 2][arow[i]] = pa[i].z; As[ac4[i] + 3][arow[i]] = pa[i].w;
            }
#pragma unroll
            for (int i = 0; i < 2; i++) {
                *(float4*)&Bsl[brow[i]][bc4[i]] = pbl[i];
                *(float4*)&Bsr[brow[i]][bc4[i]] = pbr[i];
            }
            __syncthreads();
        }
    }

    int gc = bn + tn * 4;
    float4 bll = *(const float4*)(bl + gc);
    float4 brr = *(const float4*)(br + gc);
#pragma unroll
    for (int i = 0; i < 8; i++) {
        int gr = bm + (i < 4 ? tm * 4 + i : 64 + tm * 4 + (i - 4));
        if (gr >= M) continue;
        float4 ol, orr;
        ol.x = accl[i][0] + bll.x; ol.y = accl[i][1] + bll.y;
        ol.z = accl[i][2] + bll.z; ol.w = accl[i][3] + bll.w;
        orr.x = accr[i][0] + brr.x; orr.y = accr[i][1] + brr.y;
        orr.z = accr[i][2] + brr.z; orr.w = accr[i][3] + brr.w;
        *(float4*)(xl + (size_t)gr * 512 + gc) = ol;
        *(float4*)(xr + (size_t)gr * 512 + gc) = orr;
    }
}

#define LK(mm) fmaf(fminf(mm, 0.f), NEG_SLOPE, fmaxf(mm, 0.f))

// ------- LAYER 0 fully fused: transform (K=3, per-edge recompute) + score + softmax
//         + aggregate + head-mean + bias + ELU. One wave per node, lane owns 8 channels.
__global__ __launch_bounds__(256) void fused_edge0_kernel(const int* __restrict__ off,
                                                          const int* __restrict__ csr_src,
                                                          const float* __restrict__ x,
                                                          const float* __restrict__ Wl,
                                                          const float* __restrict__ bl,
                                                          const float* __restrict__ Wr,
                                                          const float* __restrict__ br,
                                                          const float* __restrict__ att,
                                                          const float* __restrict__ bias,
                                                          float* __restrict__ hout) {
    int wid = threadIdx.x >> 6;
    int lane = threadIdx.x & 63;
    int n = blockIdx.x * 4 + wid;
    if (n >= N_NODES) return;
    int s = off[n], e = off[n + 1];
    const int loff = lane * 8;
    // per-lane weight columns (coalesced float4 loads)
    float4 wl00 = *(const float4*)(Wl + loff),        wl01 = *(const float4*)(Wl + loff + 4);
    float4 wl10 = *(const float4*)(Wl + 512 + loff),  wl11 = *(const float4*)(Wl + 512 + loff + 4);
    float4 wl20 = *(const float4*)(Wl + 1024 + loff), wl21 = *(const float4*)(Wl + 1024 + loff + 4);
    float4 bl0  = *(const float4*)(bl + loff),        bl1  = *(const float4*)(bl + loff + 4);
    float4 at0  = *(const float4*)(att + loff),       at1  = *(const float4*)(att + loff + 4);
    // xr_n = x[n] @ Wr + br
    float xn0 = x[n * 3 + 0], xn1 = x[n * 3 + 1], xn2 = x[n * 3 + 2];
    float4 xr0, xr1;
    {
        float4 wr00 = *(const float4*)(Wr + loff),        wr01 = *(const float4*)(Wr + loff + 4);
        float4 wr10 = *(const float4*)(Wr + 512 + loff),  wr11 = *(const float4*)(Wr + 512 + loff + 4);
        float4 wr20 = *(const float4*)(Wr + 1024 + loff), wr21 = *(const float4*)(Wr + 1024 + loff + 4);
        float4 br0  = *(const float4*)(br + loff),        br1  = *(const float4*)(br + loff + 4);
        xr0.x = fmaf(xn0, wr00.x, fmaf(xn1, wr10.x, fmaf(xn2, wr20.x, br0.x)));
        xr0.y = fmaf(xn0, wr00.y, fmaf(xn1, wr10.y, fmaf(xn2, wr20.y, br0.y)));
        xr0.z = fmaf(xn0, wr00.z, fmaf(xn1, wr10.z, fmaf(xn2, wr20.z, br0.z)));
        xr0.w = fmaf(xn0, wr00.w, fmaf(xn1, wr10.w, fmaf(xn2, wr20.w, br0.w)));
        xr1.x = fmaf(xn0, wr01.x, fmaf(xn1, wr11.x, fmaf(xn2, wr21.x, br1.x)));
        xr1.y = fmaf(xn0, wr01.y, fmaf(xn1, wr11.y, fmaf(xn2, wr21.y, br1.y)));
        xr1.z = fmaf(xn0, wr01.z, fmaf(xn1, wr11.z, fmaf(xn2, wr21.z, br1.z)));
        xr1.w = fmaf(xn0, wr01.w, fmaf(xn1, wr11.w, fmaf(xn2, wr21.w, br1.w)));
    }

    float mx = -1e30f, denom = 0.f;
    float a0 = 0.f, a1 = 0.f, a2 = 0.f, a3 = 0.f, a4 = 0.f, a5 = 0.f, a6 = 0.f, a7 = 0.f;

    float xs0, xs1, xs2;
    if (s < e) {
        int src = csr_src[s];
        xs0 = x[src * 3 + 0]; xs1 = x[src * 3 + 1]; xs2 = x[src * 3 + 2];
    }
    for (int p = s; p < e; p++) {
        float nx0, nx1, nx2;
        if (p + 1 < e) {
            int nxt = csr_src[p + 1];
            nx0 = x[nxt * 3 + 0]; nx1 = x[nxt * 3 + 1]; nx2 = x[nxt * 3 + 2];
        }
        // v = x[src] @ Wl + bl (8 channels/lane)
        float4 v0, v1;
        v0.x = fmaf(xs0, wl00.x, fmaf(xs1, wl10.x, fmaf(xs2, wl20.x, bl0.x)));
        v0.y = fmaf(xs0, wl00.y, fmaf(xs1, wl10.y, fmaf(xs2, wl20.y, bl0.y)));
        v0.z = fmaf(xs0, wl00.z, fmaf(xs1, wl10.z, fmaf(xs2, wl20.z, bl0.z)));
        v0.w = fmaf(xs0, wl00.w, fmaf(xs1, wl10.w, fmaf(xs2, wl20.w, bl0.w)));
        v1.x = fmaf(xs0, wl01.x, fmaf(xs1, wl11.x, fmaf(xs2, wl21.x, bl1.x)));
        v1.y = fmaf(xs0, wl01.y, fmaf(xs1, wl11.y, fmaf(xs2, wl21.y, bl1.y)));
        v1.z = fmaf(xs0, wl01.z, fmaf(xs1, wl11.z, fmaf(xs2, wl21.z, bl1.z)));
        v1.w = fmaf(xs0, wl01.w, fmaf(xs1, wl11.w, fmaf(xs2, wl21.w, bl1.w)));
        float part;
        part = LK(v0.x + xr0.x) * at0.x;
        part = fmaf(LK(v0.y + xr0.y), at0.y, part);
        part = fmaf(LK(v0.z + xr0.z), at0.z, part);
        part = fmaf(LK(v0.w + xr0.w), at0.w, part);
        part = fmaf(LK(v1.x + xr1.x), at1.x, part);
        part = fmaf(LK(v1.y + xr1.y), at1.y, part);
        part = fmaf(LK(v1.z + xr1.z), at1.z, part);
        part = fmaf(LK(v1.w + xr1.w), at1.w, part);
        part += __shfl_xor(part, 1);
        part += __shfl_xor(part, 2);
        part += __shfl_xor(part, 4);
        part += __shfl_xor(part, 8);
        float mnew = fmaxf(mx, part);
        float scale = __expf(mx - mnew);
        float w = __expf(part - mnew);
        denom = fmaf(denom, scale, w);
        a0 = fmaf(a0, scale, w * v0.x);
        a1 = fmaf(a1, scale, w * v0.y);
        a2 = fmaf(a2, scale, w * v0.z);
        a3 = fmaf(a3, scale, w * v0.w);
        a4 = fmaf(a4, scale, w * v1.x);
        a5 = fmaf(a5, scale, w * v1.y);
        a6 = fmaf(a6, scale, w * v1.z);
        a7 = fmaf(a7, scale, w * v1.w);
        mx = mnew;
        xs0 = nx0; xs1 = nx1; xs2 = nx2;
    }
    float inv = denom > 0.f ? 1.f / denom : 0.f;
    a0 *= inv; a1 *= inv; a2 *= inv; a3 *= inv;
    a4 *= inv; a5 *= inv; a6 *= inv; a7 *= inv;
    a0 += __shfl_xor(a0, 16); a0 += __shfl_xor(a0, 32);
    a1 += __shfl_xor(a1, 16); a1 += __shfl_xor(a1, 32);
    a2 += __shfl_xor(a2, 16); a2 += __shfl_xor(a2, 32);
    a3 += __shfl_xor(a3, 16); a3 += __shfl_xor(a3, 32);
    a4 += __shfl_xor(a4, 16); a4 += __shfl_xor(a4, 32);
    a5 += __shfl_xor(a5, 16); a5 += __shfl_xor(a5, 32);
    a6 += __shfl_xor(a6, 16); a6 += __shfl_xor(a6, 32);
    a7 += __shfl_xor(a7, 16); a7 += __shfl_xor(a7, 32);
    if (lane < 16) {
        float4 b0 = *(const float4*)(bias + lane * 8);
        float4 b1 = *(const float4*)(bias + lane * 8 + 4);
        float o[8];
        o[0] = fmaf(0.25f, a0, b0.x); o[1] = fmaf(0.25f, a1, b0.y);
        o[2] = fmaf(0.25f, a2, b0.z); o[3] = fmaf(0.25f, a3, b0.w);
        o[4] = fmaf(0.25f, a4, b1.x); o[5] = fmaf(0.25f, a5, b1.y);
        o[6] = fmaf(0.25f, a6, b1.z); o[7] = fmaf(0.25f, a7, b1.w);
#pragma unroll
        for (int j = 0; j < 8; j++) o[j] = o[j] > 0.f ? o[j] : (__expf(o[j]) - 1.f);
        *(float4*)(hout + (size_t)n * GAT_DIM + lane * 8) = make_float4(o[0], o[1], o[2], o[3]);
        *(float4*)(hout + (size_t)n * GAT_DIM + lane * 8 + 4) = make_float4(o[4], o[5], o[6], o[7]);
    }
}

// ------- layers 1/2: fused edge (xl/xr materialized), one wave per node ----------
__global__ __launch_bounds__(256) void fused_edge_kernel(const int* __restrict__ off,
                                                         const int* __restrict__ csr_src,
                                                         const float* __restrict__ xl,
                                                         const float* __restrict__ xr,
                                                         const float* __restrict__ att,
                                                         const float* __restrict__ bias,
                                                         float* __restrict__ hout) {
    int wid = threadIdx.x >> 6;
    int lane = threadIdx.x & 63;
    int n = blockIdx.x * 4 + wid;
    if (n >= N_NODES) return;
    int s = off[n], e = off[n + 1];
    const int loff = lane * 8;
    float4 xr0 = *(const float4*)(xr + (size_t)n * FDIM + loff);
    float4 xr1 = *(const float4*)(xr + (size_t)n * FDIM + loff + 4);
    float4 at0 = *(const float4*)(att + loff);
    float4 at1 = *(const float4*)(att + loff + 4);

    float mx = -1e30f, denom = 0.f;
    float a0 = 0.f, a1 = 0.f, a2 = 0.f, a3 = 0.f, a4 = 0.f, a5 = 0.f, a6 = 0.f, a7 = 0.f;

    float4 v0, v1;
    if (s < e) {
        int src = csr_src[s];
        const float* b = xl + (size_t)src * FDIM + loff;
        v0 = *(const float4*)b; v1 = *(const float4*)(b + 4);
    }
    for (int p = s; p < e; p++) {
        float4 n0, n1;
        if (p + 1 < e) {
            int nxt = csr_src[p + 1];
            const float* b = xl + (size_t)nxt * FDIM + loff;
            n0 = *(const float4*)b; n1 = *(const float4*)(b + 4);
        }
        float part;
        part = LK(v0.x + xr0.x) * at0.x;
        part = fmaf(LK(v0.y + xr0.y), at0.y, part);
        part = fmaf(LK(v0.z + xr0.z), at0.z, part);
        part = fmaf(LK(v0.w + xr0.w), at0.w, part);
        part = fmaf(LK(v1.x + xr1.x), at1.x, part);
        part = fmaf(LK(v1.y + xr1.y), at1.y, part);
        part = fmaf(LK(v1.z + xr1.z), at1.z, part);
        part = fmaf(LK(v1.w + xr1.w), at1.w, part);
        part += __shfl_xor(part, 1);
        part += __shfl_xor(part, 2);
        part += __shfl_xor(part, 4);
        part += __shfl_xor(part, 8);
        float mnew = fmaxf(mx, part);
        float scale = __expf(mx - mnew);
        float w = __expf(part - mnew);
        denom = fmaf(denom, scale, w);
        a0 = fmaf(a0, scale, w * v0.x);
        a1 = fmaf(a1, scale, w * v0.y);
        a2 = fmaf(a2, scale, w * v0.z);
        a3 = fmaf(a3, scale, w * v0.w);
        a4 = fmaf(a4, scale, w * v1.x);
        a5 = fmaf(a5, scale, w * v1.y);
        a6 = fmaf(a6, scale, w * v1.z);
        a7 = fmaf(a7, scale, w * v1.w);
        mx = mnew;
        v0 = n0; v1 = n1;
    }
    float inv = denom > 0.f ? 1.f / denom : 0.f;
    a0 *= inv; a1 *= inv; a2 *= inv; a3 *= inv;
    a4 *= inv; a5 *= inv; a6 *= inv; a7 *= inv;
    a0 += __shfl_xor(a0, 16); a0 += __shfl_xor(a0, 32);
    a1 += __shfl_xor(a1, 16); a1 += __shfl_xor(a1, 32);
    a2 += __shfl_xor(a2, 16); a2 += __shfl_xor(a2, 32);
    a3 += __shfl_xor(a3, 16); a3 += __shfl_xor(a3, 32);
    a4 += __shfl_xor(a4, 16); a4 += __shfl_xor(a4, 32);
    a5 += __shfl_xor(a5, 16); a5 += __shfl_xor(a5, 32);
    a6 += __shfl_xor(a6, 16); a6 += __shfl_xor(a6, 32);
    a7 += __shfl_xor(a7, 16); a7 += __shfl_xor(a7, 32);
    if (lane < 16) {
        float4 b0 = *(const float4*)(bias + lane * 8);
        float4 b1 = *(const float4*)(bias + lane * 8 + 4);
        float o[8];
        o[0] = fmaf(0.25f, a0, b0.x); o[1] = fmaf(0.25f, a1, b0.y);
        o[2] = fmaf(0.25f, a2, b0.z); o[3] = fmaf(0.25f, a3, b0.w);
        o[4] = fmaf(0.25f, a4, b1.x); o[5] = fmaf(0.25f, a5, b1.y);
        o[6] = fmaf(0.25f, a6, b1.z); o[7] = fmaf(0.25f, a7, b1.w);
#pragma unroll
        for (int j = 0; j < 8; j++) o[j] = o[j] > 0.f ? o[j] : (__expf(o[j]) - 1.f);
        *(float4*)(hout + (size_t)n * GAT_DIM + lane * 8) = make_float4(o[0], o[1], o[2], o[3]);
        *(float4*)(hout + (size_t)n * GAT_DIM + lane * 8 + 4) = make_float4(o[4], o[5], o[6], o[7]);
    }
}

// ---------------- mean pool over sorted batch (double accumulation) ----------------
#define POOL_CHUNK 64
__global__ __launch_bounds__(128) void pool_kernel(const float* __restrict__ h,
                                                   const int* __restrict__ batch,
                                                   double* __restrict__ psum,
                                                   int* __restrict__ pcnt) {
    int c = threadIdx.x;  // 0..127
    int n0 = blockIdx.x * POOL_CHUNK;
    int n1 = min(n0 + POOL_CHUNK, N_NODES);
    if (n0 >= N_NODES) return;
    double acc = 0.0;
    int cur = batch[n0];
    int cnt = 0;
    for (int n = n0; n < n1; n++) {
        int g = batch[n];
        if (g != cur) {
            atomicAdd(&psum[(size_t)cur * GAT_DIM + c], acc);
            if (c == 0) atomicAdd(&pcnt[cur], cnt);
            acc = 0.0; cnt = 0; cur = g;
        }
        acc += (double)h[(size_t)n * GAT_DIM + c];
        cnt++;
    }
    atomicAdd(&psum[(size_t)cur * GAT_DIM + c], acc);
    if (c == 0) atomicAdd(&pcnt[cur], cnt);
}

// ---------------- final linear: out[64,128] = g @ linW + linb ----------------
__global__ __launch_bounds__(128) void final_kernel(const double* __restrict__ psum,
                                                    const int* __restrict__ pcnt,
                                                    const float* __restrict__ linW,
                                                    const float* __restrict__ linb,
                                                    float* __restrict__ out) {
    int g = blockIdx.x;       // 0..63
    int j = threadIdx.x;      // 0..127
    __shared__ float gv[128];
    float cnt = (float)max(pcnt[g], 1);
    gv[j] = (float)(psum[(size_t)g * 128 + j] / (double)cnt);
    __syncthreads();
    float acc = 0.f;
    for (int c = 0; c < 128; c++) acc = fmaf(gv[c], linW[c * 128 + j], acc);
    out[(size_t)g * 128 + j] = acc + linb[j];
}

extern "C" void kernel_launch(void* const* d_in, const int* in_sizes, int n_in,
                              void* d_out, int out_size, void* d_ws, size_t ws_size,
                              hipStream_t stream) {
    const float* x    = (const float*)d_in[0];
    const int* eidx   = (const int*)d_in[1];
    const int* batch  = (const int*)d_in[2];
    const float* Wl[3] = {(const float*)d_in[3],  (const float*)d_in[9],  (const float*)d_in[15]};
    const float* bl[3] = {(const float*)d_in[4],  (const float*)d_in[10], (const float*)d_in[16]};
    const float* Wr[3] = {(const float*)d_in[5],  (const float*)d_in[11], (const float*)d_in[17]};
    const float* br[3] = {(const float*)d_in[6],  (const float*)d_in[12], (const float*)d_in[18]};
    const float* att[3] = {(const float*)d_in[7], (const float*)d_in[13], (const float*)d_in[19]};
    const float* bb[3] = {(const float*)d_in[8],  (const float*)d_in[14], (const float*)d_in[20]};
    const float* linW = (const float*)d_in[21];
    const float* linb = (const float*)d_in[22];
    float* out = (float*)d_out;

    const int* esrc = eidx;
    const int* edst = eidx + N_EDGES;

    // workspace carve-up (256B aligned)
    char* p = (char*)d_ws;
    auto alloc = [&](size_t bytes) { void* r = (void*)p; p += (bytes + 255) & ~(size_t)255; return r; };
    float* xl      = (float*)alloc((size_t)N_NODES * FDIM * 4);   // 102.4 MB
    float* xr      = (float*)alloc((size_t)N_NODES * FDIM * 4);   // 102.4 MB
    float* hbuf    = (float*)alloc((size_t)N_NODES * GAT_DIM * 4);// 25.6 MB
    int*   off     = (int*)alloc((size_t)(N_NODES + 1) * 4);
    int*   csr_src = (int*)alloc((size_t)N_EDGES * 4);
    // --- contiguous zero region: deg, cursor, psum, pcnt ---
    char* zbase = p;
    int*   deg     = (int*)alloc((size_t)N_NODES * 4);
    int*   cursor  = (int*)alloc((size_t)N_NODES * 4);
    double* psum   = (double*)alloc((size_t)N_GRAPHS * GAT_DIM * 8);
    int*   pcnt    = (int*)alloc((size_t)N_GRAPHS * 4);
    size_t zbytes = (size_t)(p - zbase);

    hipMemsetAsync(zbase, 0, zbytes, stream);

    // CSR build (dst is layer-invariant)
    deg_kernel<<<(N_EDGES + 255) / 256, 256, 0, stream>>>(edst, deg);
    scan_kernel<<<1, 1024, 0, stream>>>(deg, off);
    fill_kernel<<<(N_EDGES + 255) / 256, 256, 0, stream>>>(esrc, edst, off, cursor, csr_src);

    dim3 ggrid(512 / BN, (N_NODES + BM - 1) / BM);
    const int egrid = (N_NODES + 3) / 4;  // 4 nodes (waves) per 256-thr block

    // layer 0: fully fused (K=3 transform recomputed per edge)
    fused_edge0_kernel<<<egrid, 256, 0, stream>>>(off, csr_src, x, Wl[0], bl[0], Wr[0], br[0],
                                                  att[0], bb[0], hbuf);
    // layers 1,2
    for (int l = 1; l < 3; l++) {
        gemm_dual_kernel<<<ggrid, 256, 0, stream>>>(hbuf, Wl[l], bl[l], Wr[l], br[l],
                                                    xl, xr, N_NODES);
        fused_edge_kernel<<<egrid, 256, 0, stream>>>(off, csr_src, xl, xr, att[l], bb[l], hbuf);
    }

    pool_kernel<<<(N_NODES + POOL_CHUNK - 1) / POOL_CHUNK, 128, 0, stream>>>(hbuf, batch, psum, pcnt);
    final_kernel<<<N_GRAPHS, 128, 0, stream>>>(psum, pcnt, linW, linb, out);
}